// Round 10
// baseline (113.190 us; speedup 1.0000x reference)
//
#include <hip/hip_runtime.h>

// IGANN: per-feature 2-layer MLPs (1->16->16->1), summed over 256 features + linear term.
// R10 = R9 (LDS-resident f16 operands, zero global loads in inner loop, plain
//     launch_bounds(256) — min-waves variants all spilled) with 2x rows per block:
//     128 rows/wave (8 MFMA tiles), 512 rows/block, grid 64x16=1024 = EXACTLY 4 blocks/CU
//     (uniform, no drain tail; R9's 2048 on 1536 slots ran the last generation at 1/3 occ).
//     Weight ds_reads amortized over 8 MFMAs; weight staging halved. LDS 35.8 KB -> 4/CU.

typedef float    f32x4 __attribute__((ext_vector_type(4)));
typedef _Float16 f16x4 __attribute__((ext_vector_type(4)));
typedef __fp16   pk16x2 __attribute__((ext_vector_type(2)));

__device__ __forceinline__ f16x4 cvt4(f32x4 v) {
    pk16x2 lo = __builtin_amdgcn_cvt_pkrtz(v[0], v[1]);
    pk16x2 hi = __builtin_amdgcn_cvt_pkrtz(v[2], v[3]);
    union { unsigned u[2]; f16x4 h; } un;
    un.u[0] = __builtin_bit_cast(unsigned, lo);
    un.u[1] = __builtin_bit_cast(unsigned, hi);
    return un.h;
}

__device__ __forceinline__ f16x4 relu_h(f16x4 v) {
    f16x4 z = {};
    return __builtin_elementwise_max(v, z);
}

__device__ __forceinline__ f32x4 relu_f(f32x4 v) {
    f32x4 z = {0.f, 0.f, 0.f, 0.f};
    return __builtin_elementwise_max(v, z);
}

#define FCHUNK 16   // features per block (16 groups of 16 = 256)
#define ROWS   512  // batch rows per block (128 per wave, 8 MFMA tiles)
#define NT     8    // MFMA row-tiles per wave
#define XR     20   // x LDS row stride in f16 (40 B: b64-aligned)
#define W2R    20   // W2 LDS row stride in f16

__global__ __launch_bounds__(256) void igann_kernel(
    const float* __restrict__ x,  const float* __restrict__ la,
    const float* __restrict__ bb, const float* __restrict__ W1,
    const float* __restrict__ b1, const float* __restrict__ W2,
    const float* __restrict__ b2, const float* __restrict__ W3,
    const float* __restrict__ b3, float* __restrict__ out)
{
    const int tid = threadIdx.x;
    const int l   = tid & 63;     // lane
    const int w   = tid >> 6;     // wave in block (0..3)
    const int r   = l & 15;       // MFMA row m (A) / col n (D)
    const int g   = l >> 4;       // k-group
    const int g4  = g * 4;

    const int rb = blockIdx.x >> 4;    // row block (0..63), 512 rows each
    const int fg = blockIdx.x & 15;    // feature group (0..15)
    const int f0 = fg * FCHUNK;
    const int rowbase = rb * ROWS;

    __shared__ _Float16 xs [ROWS * XR];          // 20480 B: x slice [row][col16+pad]
    __shared__ _Float16 w2s[FCHUNK * 16 * W2R];  // 10240 B: [f][n][k16+pad]
    __shared__ _Float16 w1s[FCHUNK * 16];        //   512 B: [f][k]
    __shared__ _Float16 b1s[FCHUNK * 16];        //   512 B
    __shared__ float    b2s[FCHUNK * 16];        //  1024 B: [f][n]
    __shared__ float    w3s[FCHUNK * 16];        //  1024 B
    __shared__ float    red[ROWS];               //  2048 B   -> total 35840 B -> 4 blocks/CU

    // ---- stage x slice (coalesced: 4 lanes cover one 64-B row-slice) ----
    {
        const int rr = tid >> 2;          // 0..63
        const int c4 = (tid & 3) * 4;     // 0,4,8,12
        #pragma unroll
        for (int it = 0; it < ROWS / 64; ++it) {
            const int row = it * 64 + rr;
            f32x4 v = *(const f32x4*)(x + (size_t)(rowbase + row) * 256 + f0 + c4);
            *(f16x4*)(xs + row * XR + c4) = cvt4(v);
        }
    }
    // ---- stage W2 chunk (4096 floats; thread tid owns row (f,n)=(tid>>4,tid&15)) ----
    {
        const int f = tid >> 4, n = tid & 15;
        const float* src = W2 + ((size_t)(f0 + f) * 16 + n) * 16;
        _Float16* dst = w2s + (f * 16 + n) * W2R;
        #pragma unroll
        for (int q = 0; q < 4; ++q) {
            f32x4 v = *(const f32x4*)(src + q * 4);
            *(f16x4*)(dst + q * 4) = cvt4(v);
        }
    }
    // ---- stage W1/b1 (f16), b2/W3 (f32): one element per thread ----
    w1s[tid] = (_Float16)W1[f0 * 16 + tid];
    b1s[tid] = (_Float16)b1[f0 * 16 + tid];
    b2s[tid] = b2[f0 * 16 + tid];
    w3s[tid] = W3[f0 * 16 + tid];
    __syncthreads();

    const _Float16* xw = xs + (w * 128 + r) * XR;

    f32x4 acc[NT];    // [tile][j]: D row g4+j (batch row within tile), col r (channel)
    #pragma unroll
    for (int t = 0; t < NT; ++t) acc[t] = (f32x4){0.f, 0.f, 0.f, 0.f};

    for (int fi = 0; fi < FCHUNK; fi += 4) {   // rolled: keeps register pressure down
        f16x4 xv[NT];
        #pragma unroll
        for (int t = 0; t < NT; ++t)
            xv[t] = *(const f16x4*)(xw + t * 16 * XR + fi);

        #pragma unroll
        for (int u = 0; u < 4; ++u) {
            const int f = fi + u;
            f16x4 w1h   = *(const f16x4*)(w1s + f * 16 + g4);
            f16x4 b1h   = *(const f16x4*)(b1s + f * 16 + g4);
            f16x4 bfrag = *(const f16x4*)(w2s + (f * 16 + r) * W2R + g4);
            const float b2k = b2s[f * 16 + r];
            const float w3k = w3s[f * 16 + r];
            const f32x4 cinit = {b2k, b2k, b2k, b2k};   // b2 folded into MFMA C
            const f32x4 w3k4  = {w3k, w3k, w3k, w3k};

            #pragma unroll
            for (int t = 0; t < NT; ++t) {
                const _Float16 s = xv[t][u];
                f16x4 xb = {s, s, s, s};
                f16x4 h = relu_h(xb * w1h + b1h);       // v_pk_fma_f16 + v_pk_max_f16
                f32x4 d = __builtin_amdgcn_mfma_f32_16x16x16f16(h, bfrag, cinit, 0, 0, 0);
                acc[t] += relu_f(d) * w3k4;
            }
        }
    }

    // reduce over the 16 output channels (lane bits 0..3); r==0 lanes hold row sums
    #pragma unroll
    for (int t = 0; t < NT; ++t)
        #pragma unroll
        for (int j = 0; j < 4; ++j) {
            float v = acc[t][j];
            v += __shfl_xor(v, 1, 64);
            v += __shfl_xor(v, 2, 64);
            v += __shfl_xor(v, 4, 64);
            v += __shfl_xor(v, 8, 64);
            if (r == 0) red[w * 128 + t * 16 + g4 + j] = v;
        }
    __syncthreads();

    // ---- epilogue: thread tid owns local rows tid and tid+256 ----
    float b3s = 0.f;
    #pragma unroll
    for (int c = 0; c < FCHUNK; ++c) b3s += b3[f0 + c];   // uniform -> s_loads
    const float gconst = b3s + (fg == 0 ? bb[0] : 0.f);

    #pragma unroll
    for (int half = 0; half < 2; ++half) {
        const int row = half * 256 + tid;
        float lin = 0.f;
        const _Float16* xrow = xs + row * XR;
        #pragma unroll
        for (int c = 0; c < FCHUNK; ++c)
            lin = fmaf((float)xrow[c], la[f0 + c], lin);  // la uniform -> s_loads
        atomicAdd(out + rowbase + row, red[row] + lin + gconst);
    }
}

extern "C" void kernel_launch(void* const* d_in, const int* in_sizes, int n_in,
                              void* d_out, int out_size, void* d_ws, size_t ws_size,
                              hipStream_t stream) {
    const float* x  = (const float*)d_in[0];
    const float* la = (const float*)d_in[1];
    const float* bb = (const float*)d_in[2];
    const float* W1 = (const float*)d_in[3];
    const float* b1 = (const float*)d_in[4];
    const float* W2 = (const float*)d_in[5];
    const float* b2 = (const float*)d_in[6];
    const float* W3 = (const float*)d_in[7];
    const float* b3 = (const float*)d_in[8];
    float* out = (float*)d_out;

    (void)hipMemsetAsync(out, 0, (size_t)out_size * sizeof(float), stream);

    dim3 grid(1024), block(256);   // 64 row-blocks x 16 feature-groups = 4 blocks/CU exact
    hipLaunchKernelGGL(igann_kernel, grid, block, 0, stream,
                       x, la, bb, W1, b1, W2, b2, W3, b3, out);
}

// Round 14
// 109.131 us; speedup vs baseline: 1.0372x; 1.0372x over previous
//
#include <hip/hip_runtime.h>

// IGANN: per-feature 2-layer MLPs (1->16->16->1), summed over 256 features + linear term.
// R14 = R11 goal (LDS exactly 20480 B -> 8 blocks/CU x 256 CU = 2048 = grid, ONE uniform
//     resident generation; kernel is phase-overlap bound per R9/R10) with R11's LDS-alias
//     construct removed after 3 unexplained container failures:
//     - no red[] array: after the xor-reduce the r==0 lanes atomicAdd per-row subnet sums
//       to out directly; epilogue adds lin+consts with its own atomic (out is L2-resident,
//       2x atomics is negligible). Removes the (float*)w2s pun and BOTH post-loop barriers.
//     - LDS: xs 10240 (XR=20, R9-proven) + w2s 8192 (W2R=16 dense: bfrag wave access is a
//       contiguous 512-B block, conflict-free) + w1/b1/b2/w3 f16 2048 = 20480 exactly.
//     Plain __launch_bounds__(256): every min-waves>=4 attempt (R3/R4/R8) spilled 100s MB.

typedef float    f32x4 __attribute__((ext_vector_type(4)));
typedef _Float16 f16x4 __attribute__((ext_vector_type(4)));
typedef __fp16   pk16x2 __attribute__((ext_vector_type(2)));

__device__ __forceinline__ f16x4 cvt4(f32x4 v) {
    pk16x2 lo = __builtin_amdgcn_cvt_pkrtz(v[0], v[1]);
    pk16x2 hi = __builtin_amdgcn_cvt_pkrtz(v[2], v[3]);
    union { unsigned u[2]; f16x4 h; } un;
    un.u[0] = __builtin_bit_cast(unsigned, lo);
    un.u[1] = __builtin_bit_cast(unsigned, hi);
    return un.h;
}

__device__ __forceinline__ f16x4 relu_h(f16x4 v) {
    f16x4 z = {};
    return __builtin_elementwise_max(v, z);
}

__device__ __forceinline__ f32x4 relu_f(f32x4 v) {
    f32x4 z = {0.f, 0.f, 0.f, 0.f};
    return __builtin_elementwise_max(v, z);
}

#define FCHUNK 16   // features per block (16 groups of 16 = 256)
#define XR     20   // x LDS row stride in f16 (40 B, 8-B aligned, conflict-free — R9-proven)
#define W2R    16   // W2 LDS row stride in f16 (dense; wave reads contiguous 512 B)

__global__ __launch_bounds__(256) void igann_kernel(
    const float* __restrict__ x,  const float* __restrict__ la,
    const float* __restrict__ bb, const float* __restrict__ W1,
    const float* __restrict__ b1, const float* __restrict__ W2,
    const float* __restrict__ b2, const float* __restrict__ W3,
    const float* __restrict__ b3, float* __restrict__ out)
{
    const int tid = threadIdx.x;
    const int l   = tid & 63;     // lane
    const int w   = tid >> 6;     // wave in block (0..3)
    const int r   = l & 15;       // MFMA row m (A) / col n (D)
    const int g   = l >> 4;       // k-group
    const int g4  = g * 4;

    const int rb = blockIdx.x >> 4;    // row block (0..127), 256 rows each
    const int fg = blockIdx.x & 15;    // feature group (0..15)
    const int f0 = fg * FCHUNK;
    const int rowbase = rb * 256;

    __shared__ _Float16 xs [256 * XR];           // 10240 B: x slice [row][col16+pad]
    __shared__ _Float16 w2s[FCHUNK * 16 * W2R];  //  8192 B: [f][n][k16]
    __shared__ _Float16 w1s[FCHUNK * 16];        //   512 B: [f][k]
    __shared__ _Float16 b1s[FCHUNK * 16];        //   512 B
    __shared__ _Float16 b2s[FCHUNK * 16];        //   512 B: [f][n]
    __shared__ _Float16 w3s[FCHUNK * 16];        //   512 B   -> 20480 B total = 8 blocks/CU

    // ---- stage x slice (coalesced: 4 lanes cover one 64-B row-slice) ----
    {
        const int rr = tid >> 2;          // 0..63
        const int c4 = (tid & 3) * 4;     // 0,4,8,12
        #pragma unroll
        for (int it = 0; it < 4; ++it) {
            const int row = it * 64 + rr;
            f32x4 v = *(const f32x4*)(x + (size_t)(rowbase + row) * 256 + f0 + c4);
            *(f16x4*)(xs + row * XR + c4) = cvt4(v);
        }
    }
    // ---- stage W2 chunk (4096 floats; thread tid owns row (f,n)=(tid>>4,tid&15)) ----
    {
        const int f = tid >> 4, n = tid & 15;
        const float* src = W2 + ((size_t)(f0 + f) * 16 + n) * 16;
        _Float16* dst = w2s + (f * 16 + n) * W2R;
        #pragma unroll
        for (int q = 0; q < 4; ++q) {
            f32x4 v = *(const f32x4*)(src + q * 4);
            *(f16x4*)(dst + q * 4) = cvt4(v);
        }
    }
    // ---- stage W1/b1/b2/W3 as f16: one element per thread ----
    w1s[tid] = (_Float16)W1[f0 * 16 + tid];
    b1s[tid] = (_Float16)b1[f0 * 16 + tid];
    b2s[tid] = (_Float16)b2[f0 * 16 + tid];
    w3s[tid] = (_Float16)W3[f0 * 16 + tid];
    __syncthreads();

    const _Float16* xw = xs + (w * 64 + r) * XR;

    f32x4 acc[4];     // [tile][j]: D row g4+j (batch row within tile), col r (channel)
    #pragma unroll
    for (int t = 0; t < 4; ++t) acc[t] = (f32x4){0.f, 0.f, 0.f, 0.f};

    for (int fi = 0; fi < FCHUNK; fi += 4) {   // rolled: keeps register pressure down
        f16x4 xv[4];
        #pragma unroll
        for (int t = 0; t < 4; ++t)
            xv[t] = *(const f16x4*)(xw + t * 16 * XR + fi);

        #pragma unroll
        for (int u = 0; u < 4; ++u) {
            const int f = fi + u;
            f16x4 w1h   = *(const f16x4*)(w1s + f * 16 + g4);
            f16x4 b1h   = *(const f16x4*)(b1s + f * 16 + g4);
            f16x4 bfrag = *(const f16x4*)(w2s + (f * 16 + r) * W2R + g4);
            const float b2k = (float)b2s[f * 16 + r];
            const float w3k = (float)w3s[f * 16 + r];
            const f32x4 cinit = {b2k, b2k, b2k, b2k};   // b2 folded into MFMA C
            const f32x4 w3k4  = {w3k, w3k, w3k, w3k};

            #pragma unroll
            for (int t = 0; t < 4; ++t) {
                const _Float16 s = xv[t][u];
                f16x4 xb = {s, s, s, s};
                f16x4 h = relu_h(xb * w1h + b1h);       // v_pk_fma_f16 + v_pk_max_f16
                f32x4 d = __builtin_amdgcn_mfma_f32_16x16x16f16(h, bfrag, cinit, 0, 0, 0);
                acc[t] += relu_f(d) * w3k4;
            }
        }
    }

    // ---- reduce over 16 output channels (lane bits 0..3); r==0 lanes atomic directly ----
    #pragma unroll
    for (int t = 0; t < 4; ++t)
        #pragma unroll
        for (int j = 0; j < 4; ++j) {
            float v = acc[t][j];
            v += __shfl_xor(v, 1, 64);
            v += __shfl_xor(v, 2, 64);
            v += __shfl_xor(v, 4, 64);
            v += __shfl_xor(v, 8, 64);
            if (r == 0)
                atomicAdd(out + rowbase + w * 64 + t * 16 + g4 + j, v);
        }

    // ---- epilogue: thread tid owns local row tid (xs read-only since first barrier,
    //      so no extra __syncthreads needed) ----
    float b3s = 0.f;
    #pragma unroll
    for (int c = 0; c < FCHUNK; ++c) b3s += b3[f0 + c];   // uniform -> s_loads
    float lin = 0.f;
    const _Float16* xrow = xs + tid * XR;
    #pragma unroll
    for (int c = 0; c < FCHUNK; ++c)
        lin = fmaf((float)xrow[c], la[f0 + c], lin);       // la uniform -> s_loads
    atomicAdd(out + rowbase + tid, lin + b3s + (fg == 0 ? bb[0] : 0.f));
}

extern "C" void kernel_launch(void* const* d_in, const int* in_sizes, int n_in,
                              void* d_out, int out_size, void* d_ws, size_t ws_size,
                              hipStream_t stream) {
    const float* x  = (const float*)d_in[0];
    const float* la = (const float*)d_in[1];
    const float* bb = (const float*)d_in[2];
    const float* W1 = (const float*)d_in[3];
    const float* b1 = (const float*)d_in[4];
    const float* W2 = (const float*)d_in[5];
    const float* b2 = (const float*)d_in[6];
    const float* W3 = (const float*)d_in[7];
    const float* b3 = (const float*)d_in[8];
    float* out = (float*)d_out;

    (void)hipMemsetAsync(out, 0, (size_t)out_size * sizeof(float), stream);

    dim3 grid(2048), block(256);   // 128 row-blocks x 16 groups = 8 blocks/CU, 1 generation
    hipLaunchKernelGGL(igann_kernel, grid, block, 0, stream,
                       x, la, bb, W1, b1, W2, b2, W3, b3, out);
}